// Round 9
// baseline (685.809 us; speedup 1.0000x reference)
//
#include <hip/hip_runtime.h>
#include <hip/hip_bf16.h>
#include <math.h>

// Problem constants (fixed by the reference)
#define LTOT 4096   // H*W = 64*64
#define DCH  96     // d_inner
#define NST  16     // d_state
#define RNK  6      // dt_rank
#define CPR  38     // R + 2N
#define KDIR 4
#define NCH  16     // scan chunks per (s,b,d)  (= waves per block)
#define CHUNK (LTOT / NCH)   // 256 steps per chunk

// Direction index maps (involutions; also the path_overlay inverse maps).
__device__ __forceinline__ int dir_idx(int k, int l) {
  int a = l >> 6, c = l & 63;          // l = a*64 + c
  if (k == 0) return l;                // HW order
  if (k == 1) return (c << 6) + a;     // WH (transpose) order
  if (k == 2) return 4095 - l;         // reversed HW
  return ((63 - c) << 6) + (63 - a);   // reversed WH
}

// DPP row_shl fused add: lane i += lane i+N within its 16-lane DPP row.
// After stages 8,4,2,1 lane n==0 of each row holds the 16-lane sum.
template <int CTRL>
__device__ __forceinline__ float row_shl_add(float p) {
  int moved = __builtin_amdgcn_update_dpp(0, __float_as_int(p), CTRL, 0xF, 0xF, true);
  return p + __int_as_float(moved);
}
__device__ __forceinline__ float reduce16(float p) {
  p = row_shl_add<0x108>(p);  // row_shl:8
  p = row_shl_add<0x104>(p);  // row_shl:4
  p = row_shl_add<0x102>(p);  // row_shl:2
  p = row_shl_add<0x101>(p);  // row_shl:1
  return p;
}

// ---------------------------------------------------------------------------
// Kernel 1: projections.  thread = one l for one (s,b,k).
// delta [s][b][k][d][l];  B/C in [s][b][k][n][l]  (row-major over l so the
// scan reads float4 over 4 consecutive steps per lane).
// ---------------------------------------------------------------------------
__global__ __launch_bounds__(256) void proj_kernel(
    const float* __restrict__ x, const float* __restrict__ y,
    const float* __restrict__ xw_d, const float* __restrict__ dtw_d, const float* __restrict__ dtb_d,
    const float* __restrict__ xw_c, const float* __restrict__ dtw_c, const float* __restrict__ dtb_c,
    float* __restrict__ deltaBuf, float* __restrict__ BBuf, float* __restrict__ CBuf)
{
  int l  = blockIdx.x * 256 + threadIdx.x;
  int k  = blockIdx.y;
  int sb = blockIdx.z;
  int s  = sb >> 2, b = sb & 3;

  const float* xin = s ? y     : x;
  const float* xw  = s ? xw_c  : xw_d;   // [K][38][96]
  const float* dtw = s ? dtw_c : dtw_d;  // [K][96][6]
  const float* dtb = s ? dtb_c : dtb_d;  // [K][96]

  int pos = dir_idx(k, l);
  const float* xb = xin + (size_t)b * DCH * LTOT;

  float acc[CPR];
  #pragma unroll
  for (int c = 0; c < CPR; ++c) acc[c] = 0.f;

  const float* Wk = xw + k * CPR * DCH;
  for (int d = 0; d < DCH; ++d) {
    float xv = xb[(size_t)d * LTOT + pos];
    #pragma unroll
    for (int c = 0; c < CPR; ++c) acc[c] = fmaf(xv, Wk[c * DCH + d], acc[c]);
  }

  const float* dwk = dtw + k * DCH * RNK;
  const float* dbk = dtb + k * DCH;
  float* dOut = deltaBuf + ((size_t)((s * 4 + b) * KDIR + k) * DCH) * LTOT + l;
  for (int d = 0; d < DCH; ++d) {
    float t = dbk[d];
    #pragma unroll
    for (int r = 0; r < RNK; ++r) t = fmaf(acc[r], dwk[d * RNK + r], t);
    float sp = (t > 20.f) ? t : log1pf(__expf(t));   // softplus
    dOut[(size_t)d * LTOT] = sp;
  }

  float* Bo = BBuf + ((size_t)((s * 4 + b) * KDIR + k) * NST) * LTOT + l;
  float* Co = CBuf + ((size_t)((s * 4 + b) * KDIR + k) * NST) * LTOT + l;
  #pragma unroll
  for (int nn = 0; nn < NST; ++nn) {
    Bo[(size_t)nn * LTOT] = acc[RNK + nn];
    Co[(size_t)nn * LTOT] = acc[RNK + NST + nn];
  }
}

// ---------------------------------------------------------------------------
// Kernel 2: chunked selective scan + in-kernel path overlay, fused per (s,b,d).
// Block = 1024 threads = 16 waves; wave c owns chunk c (256 steps = 4 rows
// of 64). Lane = (k<<4)|n.  Wrap handling is row-aligned (only the last step
// of each 64-row wraps -> compile-time, zero per-step selects).  B/C are
// float4 per 4 steps.  DPP reduces batched 4-at-a-time; one exec-masked
// atomic block per 4 steps.
// ---------------------------------------------------------------------------
__global__ __launch_bounds__(1024) void scan_kernel(
    const float* __restrict__ x, const float* __restrict__ y,
    const float* __restrict__ Alog_d, const float* __restrict__ Ds_d,
    const float* __restrict__ Alog_c, const float* __restrict__ Ds_c,
    const float* __restrict__ deltaBuf, const float* __restrict__ BBuf,
    const float* __restrict__ CBuf, float* __restrict__ yyBuf)
{
  __shared__ float yy[LTOT];        // 16 KB merged overlay accumulator
  __shared__ float xrow[LTOT];      // 16 KB staged x row
  __shared__ float hloc[NCH][64];
  __shared__ float Pc[NCH][64];
  __shared__ float hin[NCH][64];

  int tid  = threadIdx.x;
  int c    = tid >> 6;              // chunk id = wave id
  int lane = tid & 63;
  int k = lane >> 4, n = lane & 15;
  int d = blockIdx.x, b = blockIdx.y, s = blockIdx.z;

  const float* xin  = s ? y      : x;
  const float* Alog = s ? Alog_c : Alog_d;
  const float* Dsp  = s ? Ds_c   : Ds_d;

  float A2 = -__expf(Alog[(k * DCH + d) * NST + n]) * 1.44269504088896341f; // A*log2(e)

  // cooperative init: zero yy, stage x row (coalesced float4)
  const float* xb = xin + (size_t)(b * DCH + d) * LTOT;
  {
    float4 xv = ((const float4*)xb)[tid];
    ((float4*)xrow)[tid] = xv;
    ((float4*)yy)[tid] = make_float4(0.f, 0.f, 0.f, 0.f);
  }
  __syncthreads();

  const float* dbase = deltaBuf + ((size_t)(((s * 4 + b) * KDIR + k) * DCH + d)) * LTOT;
  const float* Brow  = BBuf + ((size_t)((s * 4 + b) * KDIR + k) * NST + n) * LTOT;
  const float* Crow  = CBuf + ((size_t)(((1 - s) * 4 + b) * KDIR + k) * NST + n) * LTOT; // crossed
  const int l0beg = c * CHUNK;

  // incremental pos (byte offsets): per-k step delta + wrap delta at row end
  const int dpn  = (k & 2 ? -1 : 1) * (k & 1 ? 64 : 1);
  const int dpw  = (k & 1) ? ((k & 2) ? 4031 : -4031) : dpn;
  const int dpnB = dpn * 4, dpwB = dpw * 4;

  // ---- phase 1: local scan (h0=0), accumulate sum of delta ----
  float h = 0.f, sumd = 0.f;
  {
    int posB = dir_idx(k, l0beg) * 4;
    for (int row = 0; row < CHUNK / 64; ++row) {
      const float* dr = dbase + l0beg + row * 64;
      const float* br = Brow  + l0beg + row * 64;
      #pragma unroll
      for (int g = 0; g < 16; ++g) {
        float4 dv = ((const float4*)dr)[g];
        float4 bv = ((const float4*)br)[g];
        { float u = *(const float*)((const char*)xrow + posB);
          sumd += dv.x; h = fmaf(h, exp2f(dv.x * A2), dv.x * u * bv.x); posB += dpnB; }
        { float u = *(const float*)((const char*)xrow + posB);
          sumd += dv.y; h = fmaf(h, exp2f(dv.y * A2), dv.y * u * bv.y); posB += dpnB; }
        { float u = *(const float*)((const char*)xrow + posB);
          sumd += dv.z; h = fmaf(h, exp2f(dv.z * A2), dv.z * u * bv.z); posB += dpnB; }
        { float u = *(const float*)((const char*)xrow + posB);
          sumd += dv.w; h = fmaf(h, exp2f(dv.w * A2), dv.w * u * bv.w);
          posB += (g == 15) ? dpwB : dpnB; }   // compile-time select: row end only
      }
    }
  }
  hloc[c][lane] = h;
  Pc[c][lane]   = exp2f(A2 * sumd);
  __syncthreads();

  // ---- phase 2: carry scan over chunks (wave 0; exact, linear recurrence) ----
  if (tid < 64) {
    float hh = 0.f;
    hin[0][lane] = 0.f;
    for (int cc = 1; cc < NCH; ++cc) {
      hh = fmaf(Pc[cc - 1][lane], hh, hloc[cc - 1][lane]);
      hin[cc][lane] = hh;
    }
  }
  __syncthreads();

  // ---- phase 3: full scan from true carry-in, y + overlay ----
  h = hin[c][lane];
  {
    int posB = dir_idx(k, l0beg) * 4;
    for (int row = 0; row < CHUNK / 64; ++row) {
      const float* dr = dbase + l0beg + row * 64;
      const float* br = Brow  + l0beg + row * 64;
      const float* cr = Crow  + l0beg + row * 64;
      #pragma unroll
      for (int g = 0; g < 16; ++g) {
        float4 dv = ((const float4*)dr)[g];
        float4 bv = ((const float4*)br)[g];
        float4 cv = ((const float4*)cr)[g];
        int q0 = posB;
        float u0 = *(const float*)((const char*)xrow + q0);
        h = fmaf(h, exp2f(dv.x * A2), dv.x * u0 * bv.x);
        float p0 = h * cv.x;
        int q1 = q0 + dpnB;
        float u1 = *(const float*)((const char*)xrow + q1);
        h = fmaf(h, exp2f(dv.y * A2), dv.y * u1 * bv.y);
        float p1 = h * cv.y;
        int q2 = q1 + dpnB;
        float u2 = *(const float*)((const char*)xrow + q2);
        h = fmaf(h, exp2f(dv.z * A2), dv.z * u2 * bv.z);
        float p2 = h * cv.z;
        int q3 = q2 + dpnB;
        float u3 = *(const float*)((const char*)xrow + q3);
        h = fmaf(h, exp2f(dv.w * A2), dv.w * u3 * bv.w);
        float p3 = h * cv.w;
        posB = q3 + ((g == 15) ? dpwB : dpnB);
        // 4 independent DPP trees (ILP), then one masked atomic block
        p0 = reduce16(p0);
        p1 = reduce16(p1);
        p2 = reduce16(p2);
        p3 = reduce16(p3);
        if (n == 0) {
          atomicAdd((float*)((char*)yy + q0), p0);
          atomicAdd((float*)((char*)yy + q1), p1);
          atomicAdd((float*)((char*)yy + q2), p2);
          atomicAdd((float*)((char*)yy + q3), p3);
        }
      }
    }
  }
  __syncthreads();

  // writeback with hoisted D-skip term: sum_k u*Dv_k = xrow[m] * Dsum
  float Dsum = Dsp[0 * DCH + d] + Dsp[1 * DCH + d] + Dsp[2 * DCH + d] + Dsp[3 * DCH + d];
  float* out = yyBuf + (size_t)((s * 4 + b) * DCH + d) * LTOT;
  {
    float4 v  = ((const float4*)yy)[tid];
    float4 xv = ((const float4*)xrow)[tid];
    v.x = fmaf(xv.x, Dsum, v.x);
    v.y = fmaf(xv.y, Dsum, v.y);
    v.z = fmaf(xv.z, Dsum, v.z);
    v.w = fmaf(xv.w, Dsum, v.w);
    ((float4*)out)[tid] = v;
  }
}

// ---------------------------------------------------------------------------
// Kernel 3: layernorm over channels + final transpose to [B,D,H,W].
// ---------------------------------------------------------------------------
__global__ __launch_bounds__(256) void merge_ln_kernel(
    const float* __restrict__ yyBuf,
    const float* __restrict__ ln1s, const float* __restrict__ ln1b,
    const float* __restrict__ ln2s, const float* __restrict__ ln2b,
    float* __restrict__ out)
{
  int p = blockIdx.x * 256 + threadIdx.x;
  int b = blockIdx.y, s = blockIdx.z;

  const float* base = yyBuf + ((size_t)(s * 4 + b) * DCH) * LTOT + p;
  float v[DCH];
  float m = 0.f;
  #pragma unroll
  for (int d = 0; d < DCH; ++d) { v[d] = base[(size_t)d * LTOT]; m += v[d]; }
  m *= (1.f / DCH);
  float var = 0.f;
  #pragma unroll
  for (int d = 0; d < DCH; ++d) { float t = v[d] - m; var = fmaf(t, t, var); }
  var *= (1.f / DCH);
  float r = rsqrtf(var + 1e-5f);

  const float* sc = s ? ln2s : ln1s;
  const float* bi = s ? ln2b : ln1b;
  float* ob = out + ((size_t)(s * 4 + b) * DCH) * LTOT + p;
  #pragma unroll
  for (int d = 0; d < DCH; ++d) ob[(size_t)d * LTOT] = (v[d] - m) * r * sc[d] + bi[d];
}

// ---------------------------------------------------------------------------
extern "C" void kernel_launch(void* const* d_in, const int* in_sizes, int n_in,
                              void* d_out, int out_size, void* d_ws, size_t ws_size,
                              hipStream_t stream)
{
  const float* x      = (const float*)d_in[0];
  const float* y      = (const float*)d_in[1];
  const float* xw_d   = (const float*)d_in[2];
  const float* dtw_d  = (const float*)d_in[3];
  const float* dtb_d  = (const float*)d_in[4];
  const float* Alog_d = (const float*)d_in[5];
  const float* Ds_d   = (const float*)d_in[6];
  const float* xw_c   = (const float*)d_in[7];
  const float* dtw_c  = (const float*)d_in[8];
  const float* dtb_c  = (const float*)d_in[9];
  const float* Alog_c = (const float*)d_in[10];
  const float* Ds_c   = (const float*)d_in[11];
  const float* ln1s   = (const float*)d_in[12];
  const float* ln1b   = (const float*)d_in[13];
  const float* ln2s   = (const float*)d_in[14];
  const float* ln2b   = (const float*)d_in[15];

  float* ws = (float*)d_ws;
  float* deltaBuf = ws;
  float* BBuf  = deltaBuf + (size_t)2 * 4 * KDIR * DCH * LTOT;
  float* CBuf  = BBuf + (size_t)2 * 4 * KDIR * NST * LTOT;
  float* yyBuf = CBuf + (size_t)2 * 4 * KDIR * NST * LTOT;
  float* outF  = (float*)d_out;

  dim3 pg(LTOT / 256, KDIR, 8);   // (l-chunks, k, s*4+b)
  hipLaunchKernelGGL(proj_kernel, pg, dim3(256), 0, stream,
                     x, y, xw_d, dtw_d, dtb_d, xw_c, dtw_c, dtb_c,
                     deltaBuf, BBuf, CBuf);

  dim3 sg(DCH, 4, 2);             // (d, b, s): one 16-wave block each
  hipLaunchKernelGGL(scan_kernel, sg, dim3(1024), 0, stream,
                     x, y, Alog_d, Ds_d, Alog_c, Ds_c,
                     deltaBuf, BBuf, CBuf, yyBuf);

  dim3 mg(LTOT / 256, 4, 2);      // (p-chunks, b, s)
  hipLaunchKernelGGL(merge_ln_kernel, mg, dim3(256), 0, stream,
                     yyBuf, ln1s, ln1b, ln2s, ln2b, outF);
}

// Round 10
// 400.210 us; speedup vs baseline: 1.7136x; 1.7136x over previous
//
#include <hip/hip_runtime.h>
#include <hip/hip_bf16.h>
#include <math.h>

// Problem constants (fixed by the reference)
#define LTOT 4096   // H*W = 64*64
#define DCH  96     // d_inner
#define NST  16     // d_state
#define RNK  6      // dt_rank
#define CPR  38     // R + 2N
#define KDIR 4
#define NCH  16     // scan chunks per (s,b,d)  (= waves per block)
#define CHUNK (LTOT / NCH)   // 256 steps per chunk

// Direction index maps (involutions; also the path_overlay inverse maps).
__device__ __forceinline__ int dir_idx(int k, int l) {
  int a = l >> 6, c = l & 63;          // l = a*64 + c
  if (k == 0) return l;                // HW order
  if (k == 1) return (c << 6) + a;     // WH (transpose) order
  if (k == 2) return 4095 - l;         // reversed HW
  return ((63 - c) << 6) + (63 - a);   // reversed WH
}

// DPP row_shl fused add: lane i += lane i+N within its 16-lane DPP row.
// After stages 8,4,2,1 lane n==0 of each row holds the 16-lane sum.
template <int CTRL>
__device__ __forceinline__ float row_shl_add(float p) {
  int moved = __builtin_amdgcn_update_dpp(0, __float_as_int(p), CTRL, 0xF, 0xF, true);
  return p + __int_as_float(moved);
}
__device__ __forceinline__ float reduce16(float p) {
  p = row_shl_add<0x108>(p);  // row_shl:8
  p = row_shl_add<0x104>(p);  // row_shl:4
  p = row_shl_add<0x102>(p);  // row_shl:2
  p = row_shl_add<0x101>(p);  // row_shl:1
  return p;
}

// ---------------------------------------------------------------------------
// Kernel 1: projections.  thread = one l for one (s,b,k).
// delta [s][b][k][d][l];  B/C interleaved [s][b][k][l][n] (n fastest) so the
// scan's 16 n-lanes of each k-group read 64 contiguous bytes per step
// (wave-coalesced; ~4-8 cache lines per wave per step -- L1-friendly).
// ---------------------------------------------------------------------------
__global__ __launch_bounds__(256) void proj_kernel(
    const float* __restrict__ x, const float* __restrict__ y,
    const float* __restrict__ xw_d, const float* __restrict__ dtw_d, const float* __restrict__ dtb_d,
    const float* __restrict__ xw_c, const float* __restrict__ dtw_c, const float* __restrict__ dtb_c,
    float* __restrict__ deltaBuf, float* __restrict__ BBuf, float* __restrict__ CBuf)
{
  int l  = blockIdx.x * 256 + threadIdx.x;
  int k  = blockIdx.y;
  int sb = blockIdx.z;
  int s  = sb >> 2, b = sb & 3;

  const float* xin = s ? y     : x;
  const float* xw  = s ? xw_c  : xw_d;   // [K][38][96]
  const float* dtw = s ? dtw_c : dtw_d;  // [K][96][6]
  const float* dtb = s ? dtb_c : dtb_d;  // [K][96]

  int pos = dir_idx(k, l);
  const float* xb = xin + (size_t)b * DCH * LTOT;

  float acc[CPR];
  #pragma unroll
  for (int c = 0; c < CPR; ++c) acc[c] = 0.f;

  const float* Wk = xw + k * CPR * DCH;
  for (int d = 0; d < DCH; ++d) {
    float xv = xb[(size_t)d * LTOT + pos];
    #pragma unroll
    for (int c = 0; c < CPR; ++c) acc[c] = fmaf(xv, Wk[c * DCH + d], acc[c]);
  }

  const float* dwk = dtw + k * DCH * RNK;
  const float* dbk = dtb + k * DCH;
  float* dOut = deltaBuf + ((size_t)((s * 4 + b) * KDIR + k) * DCH) * LTOT + l;
  for (int d = 0; d < DCH; ++d) {
    float t = dbk[d];
    #pragma unroll
    for (int r = 0; r < RNK; ++r) t = fmaf(acc[r], dwk[d * RNK + r], t);
    float sp = (t > 20.f) ? t : log1pf(__expf(t));   // softplus
    dOut[(size_t)d * LTOT] = sp;
  }

  // interleaved [l][n] writes: fully coalesced float4s
  float* Bo = BBuf + ((size_t)((s * 4 + b) * KDIR + k) * LTOT + l) * NST;
  float* Co = CBuf + ((size_t)((s * 4 + b) * KDIR + k) * LTOT + l) * NST;
  #pragma unroll
  for (int q = 0; q < 4; ++q) {
    float4 bv = make_float4(acc[RNK + 4*q], acc[RNK + 4*q+1], acc[RNK + 4*q+2], acc[RNK + 4*q+3]);
    float4 cv = make_float4(acc[RNK+NST + 4*q], acc[RNK+NST + 4*q+1], acc[RNK+NST + 4*q+2], acc[RNK+NST + 4*q+3]);
    ((float4*)Bo)[q] = bv;
    ((float4*)Co)[q] = cv;
  }
}

// ---------------------------------------------------------------------------
// Kernel 2: chunked selective scan + in-kernel path overlay, fused per (s,b,d).
// Block = 1024 threads = 16 waves; wave c owns chunk c (256 steps = 4 rows
// of 64).  Lane = (k<<4)|n.  Per-step cost minimized:
//   - incremental pos with UNCONDITIONAL row-end wrap correction (0 selects)
//   - exp2 with prefolded log2e
//   - 4-step batches: 4 ILP DPP reduce trees + one exec-masked atomic block
//   - B/C [l][n] layout: wave-coalesced scalar loads (VMEM pipe, L1-friendly)
// ---------------------------------------------------------------------------
__global__ __launch_bounds__(1024) void scan_kernel(
    const float* __restrict__ x, const float* __restrict__ y,
    const float* __restrict__ Alog_d, const float* __restrict__ Ds_d,
    const float* __restrict__ Alog_c, const float* __restrict__ Ds_c,
    const float* __restrict__ deltaBuf, const float* __restrict__ BBuf,
    const float* __restrict__ CBuf, float* __restrict__ yyBuf)
{
  __shared__ float yy[LTOT];        // 16 KB merged overlay accumulator
  __shared__ float xrow[LTOT];      // 16 KB staged x row
  __shared__ float hloc[NCH][64];
  __shared__ float Pc[NCH][64];
  __shared__ float hin[NCH][64];

  int tid  = threadIdx.x;
  int c    = tid >> 6;              // chunk id = wave id
  int lane = tid & 63;
  int k = lane >> 4, n = lane & 15;
  int d = blockIdx.x, b = blockIdx.y, s = blockIdx.z;

  const float* xin  = s ? y      : x;
  const float* Alog = s ? Alog_c : Alog_d;
  const float* Dsp  = s ? Ds_c   : Ds_d;

  float A2 = -__expf(Alog[(k * DCH + d) * NST + n]) * 1.44269504088896341f; // A*log2(e)

  // cooperative init: zero yy, stage x row (coalesced float4)
  const float* xb = xin + (size_t)(b * DCH + d) * LTOT;
  {
    float4 xv = ((const float4*)xb)[tid];
    ((float4*)xrow)[tid] = xv;
    ((float4*)yy)[tid] = make_float4(0.f, 0.f, 0.f, 0.f);
  }
  __syncthreads();

  const float* dbase = deltaBuf + ((size_t)(((s * 4 + b) * KDIR + k) * DCH + d)) * LTOT;
  const float* Bbase = BBuf + ((size_t)((s * 4 + b) * KDIR + k)) * LTOT * NST;
  const float* Cbase = CBuf + ((size_t)(((1 - s) * 4 + b) * KDIR + k)) * LTOT * NST; // crossed
  const int l0beg = c * CHUNK;

  // incremental pos (byte offsets): per-k step delta; row-end wrap correction
  const int dpn  = (k & 2 ? -1 : 1) * (k & 1 ? 64 : 1);
  const int dpw  = (k & 1) ? ((k & 2) ? 4031 : -4031) : dpn;
  const int dpnB = dpn * 4, dpwB = dpw * 4;
  const int rowFix = dpwB - dpnB;    // 0 for k=0,2

  // ---- phase 1: local scan (h0=0), accumulate sum of delta ----
  float h = 0.f, sumd = 0.f;
  {
    int posB = dir_idx(k, l0beg) * 4;
    const float* dp = dbase + l0beg;
    const float* Bp = Bbase + (size_t)l0beg * NST + n;
    for (int row = 0; row < CHUNK / 64; ++row) {
      #pragma unroll 8
      for (int g = 0; g < 16; ++g) {
        float4 dv = *(const float4*)dp;  dp += 4;
        float b0 = Bp[0 * NST], b1 = Bp[1 * NST], b2 = Bp[2 * NST], b3 = Bp[3 * NST];
        Bp += 4 * NST;
        float u;
        u = *(const float*)((const char*)xrow + posB); posB += dpnB;
        sumd += dv.x; h = fmaf(h, exp2f(dv.x * A2), dv.x * u * b0);
        u = *(const float*)((const char*)xrow + posB); posB += dpnB;
        sumd += dv.y; h = fmaf(h, exp2f(dv.y * A2), dv.y * u * b1);
        u = *(const float*)((const char*)xrow + posB); posB += dpnB;
        sumd += dv.z; h = fmaf(h, exp2f(dv.z * A2), dv.z * u * b2);
        u = *(const float*)((const char*)xrow + posB); posB += dpnB;
        sumd += dv.w; h = fmaf(h, exp2f(dv.w * A2), dv.w * u * b3);
      }
      posB += rowFix;   // unconditional row-end wrap correction
    }
  }
  hloc[c][lane] = h;
  Pc[c][lane]   = exp2f(A2 * sumd);
  __syncthreads();

  // ---- phase 2: carry scan over chunks (wave 0; exact, linear recurrence) ----
  if (tid < 64) {
    float hh = 0.f;
    hin[0][lane] = 0.f;
    for (int cc = 1; cc < NCH; ++cc) {
      hh = fmaf(Pc[cc - 1][lane], hh, hloc[cc - 1][lane]);
      hin[cc][lane] = hh;
    }
  }
  __syncthreads();

  // ---- phase 3: full scan from true carry-in, y + overlay ----
  h = hin[c][lane];
  {
    int posB = dir_idx(k, l0beg) * 4;
    const float* dp = dbase + l0beg;
    const float* Bp = Bbase + (size_t)l0beg * NST + n;
    const float* Cp = Cbase + (size_t)l0beg * NST + n;
    for (int row = 0; row < CHUNK / 64; ++row) {
      #pragma unroll 4
      for (int g = 0; g < 16; ++g) {
        float4 dv = *(const float4*)dp;  dp += 4;
        float b0 = Bp[0 * NST], b1 = Bp[1 * NST], b2 = Bp[2 * NST], b3 = Bp[3 * NST];
        float c0 = Cp[0 * NST], c1 = Cp[1 * NST], c2 = Cp[2 * NST], c3 = Cp[3 * NST];
        Bp += 4 * NST;  Cp += 4 * NST;
        int q0 = posB;
        float u0 = *(const float*)((const char*)xrow + q0);
        h = fmaf(h, exp2f(dv.x * A2), dv.x * u0 * b0);
        float p0 = h * c0;
        int q1 = q0 + dpnB;
        float u1 = *(const float*)((const char*)xrow + q1);
        h = fmaf(h, exp2f(dv.y * A2), dv.y * u1 * b1);
        float p1 = h * c1;
        int q2 = q1 + dpnB;
        float u2 = *(const float*)((const char*)xrow + q2);
        h = fmaf(h, exp2f(dv.z * A2), dv.z * u2 * b2);
        float p2 = h * c2;
        int q3 = q2 + dpnB;
        float u3 = *(const float*)((const char*)xrow + q3);
        h = fmaf(h, exp2f(dv.w * A2), dv.w * u3 * b3);
        float p3 = h * c3;
        posB = q3 + dpnB;
        // 4 independent DPP trees (ILP), then one masked atomic block
        p0 = reduce16(p0);
        p1 = reduce16(p1);
        p2 = reduce16(p2);
        p3 = reduce16(p3);
        if (n == 0) {
          atomicAdd((float*)((char*)yy + q0), p0);
          atomicAdd((float*)((char*)yy + q1), p1);
          atomicAdd((float*)((char*)yy + q2), p2);
          atomicAdd((float*)((char*)yy + q3), p3);
        }
      }
      posB += rowFix;   // unconditional row-end wrap correction
    }
  }
  __syncthreads();

  // writeback with hoisted D-skip term: sum_k u*Dv_k = xrow[m] * Dsum
  float Dsum = Dsp[0 * DCH + d] + Dsp[1 * DCH + d] + Dsp[2 * DCH + d] + Dsp[3 * DCH + d];
  float* out = yyBuf + (size_t)((s * 4 + b) * DCH + d) * LTOT;
  {
    float4 v  = ((const float4*)yy)[tid];
    float4 xv = ((const float4*)xrow)[tid];
    v.x = fmaf(xv.x, Dsum, v.x);
    v.y = fmaf(xv.y, Dsum, v.y);
    v.z = fmaf(xv.z, Dsum, v.z);
    v.w = fmaf(xv.w, Dsum, v.w);
    ((float4*)out)[tid] = v;
  }
}

// ---------------------------------------------------------------------------
// Kernel 3: layernorm over channels + final transpose to [B,D,H,W].
// ---------------------------------------------------------------------------
__global__ __launch_bounds__(256) void merge_ln_kernel(
    const float* __restrict__ yyBuf,
    const float* __restrict__ ln1s, const float* __restrict__ ln1b,
    const float* __restrict__ ln2s, const float* __restrict__ ln2b,
    float* __restrict__ out)
{
  int p = blockIdx.x * 256 + threadIdx.x;
  int b = blockIdx.y, s = blockIdx.z;

  const float* base = yyBuf + ((size_t)(s * 4 + b) * DCH) * LTOT + p;
  float v[DCH];
  float m = 0.f;
  #pragma unroll
  for (int d = 0; d < DCH; ++d) { v[d] = base[(size_t)d * LTOT]; m += v[d]; }
  m *= (1.f / DCH);
  float var = 0.f;
  #pragma unroll
  for (int d = 0; d < DCH; ++d) { float t = v[d] - m; var = fmaf(t, t, var); }
  var *= (1.f / DCH);
  float r = rsqrtf(var + 1e-5f);

  const float* sc = s ? ln2s : ln1s;
  const float* bi = s ? ln2b : ln1b;
  float* ob = out + ((size_t)(s * 4 + b) * DCH) * LTOT + p;
  #pragma unroll
  for (int d = 0; d < DCH; ++d) ob[(size_t)d * LTOT] = (v[d] - m) * r * sc[d] + bi[d];
}

// ---------------------------------------------------------------------------
extern "C" void kernel_launch(void* const* d_in, const int* in_sizes, int n_in,
                              void* d_out, int out_size, void* d_ws, size_t ws_size,
                              hipStream_t stream)
{
  const float* x      = (const float*)d_in[0];
  const float* y      = (const float*)d_in[1];
  const float* xw_d   = (const float*)d_in[2];
  const float* dtw_d  = (const float*)d_in[3];
  const float* dtb_d  = (const float*)d_in[4];
  const float* Alog_d = (const float*)d_in[5];
  const float* Ds_d   = (const float*)d_in[6];
  const float* xw_c   = (const float*)d_in[7];
  const float* dtw_c  = (const float*)d_in[8];
  const float* dtb_c  = (const float*)d_in[9];
  const float* Alog_c = (const float*)d_in[10];
  const float* Ds_c   = (const float*)d_in[11];
  const float* ln1s   = (const float*)d_in[12];
  const float* ln1b   = (const float*)d_in[13];
  const float* ln2s   = (const float*)d_in[14];
  const float* ln2b   = (const float*)d_in[15];

  float* ws = (float*)d_ws;
  float* deltaBuf = ws;
  float* BBuf  = deltaBuf + (size_t)2 * 4 * KDIR * DCH * LTOT;
  float* CBuf  = BBuf + (size_t)2 * 4 * KDIR * NST * LTOT;
  float* yyBuf = CBuf + (size_t)2 * 4 * KDIR * NST * LTOT;
  float* outF  = (float*)d_out;

  dim3 pg(LTOT / 256, KDIR, 8);   // (l-chunks, k, s*4+b)
  hipLaunchKernelGGL(proj_kernel, pg, dim3(256), 0, stream,
                     x, y, xw_d, dtw_d, dtb_d, xw_c, dtw_c, dtb_c,
                     deltaBuf, BBuf, CBuf);

  dim3 sg(DCH, 4, 2);             // (d, b, s): one 16-wave block each
  hipLaunchKernelGGL(scan_kernel, sg, dim3(1024), 0, stream,
                     x, y, Alog_d, Ds_d, Alog_c, Ds_c,
                     deltaBuf, BBuf, CBuf, yyBuf);

  dim3 mg(LTOT / 256, 4, 2);      // (p-chunks, b, s)
  hipLaunchKernelGGL(merge_ln_kernel, mg, dim3(256), 0, stream,
                     yyBuf, ln1s, ln1b, ln2s, ln2b, outF);
}